// Round 1
// baseline (238133.643 us; speedup 1.0000x reference)
//
#include <hip/hip_runtime.h>
#include <hip/hip_cooperative_groups.h>

namespace cg = cooperative_groups;

#define SEQ 8192
#define NT  2048
#define LOG2E 1.4426950408889634f
#define LN2   0.6931471805599453f

// Double-buffered forward variables (log2 domain) + gold score.
// Device globals: no dependence on ws_size; re-initialized every call.
__device__ float g_fv[2][NT];
__device__ float g_gold;

// ---- init: fv0 = (T_start + feats[0]) * log2(e) ----
__global__ void crf_init(const float* __restrict__ feats,
                         const float* __restrict__ tstart) {
    int j = blockIdx.x * blockDim.x + threadIdx.x;
    if (j < NT) g_fv[0][j] = (tstart[j] + feats[j]) * LOG2E;
}

// ---- gold path score (natural log domain) ----
__global__ void crf_gold(const float* __restrict__ feats,
                         const float* __restrict__ trans,
                         const float* __restrict__ tstart,
                         const float* __restrict__ tstop,
                         const int*   __restrict__ tags) {
    __shared__ float part[16];
    int tid = threadIdx.x;
    float acc = 0.f;
    for (int t = 1 + tid; t < SEQ; t += 1024) {
        int cur = tags[t], prev = tags[t - 1];
        acc += trans[(size_t)cur * NT + prev] + feats[(size_t)t * NT + cur];
    }
    #pragma unroll
    for (int m = 1; m < 64; m <<= 1) acc += __shfl_xor(acc, m, 64);
    if ((tid & 63) == 0) part[tid >> 6] = acc;
    __syncthreads();
    if (tid == 0) {
        float S = 0.f;
        #pragma unroll
        for (int w = 0; w < 16; ++w) S += part[w];
        int t0 = tags[0], tl = tags[SEQ - 1];
        g_gold = S + tstart[t0] + feats[t0] + tstop[tl];
    }
}

// ---- main recurrence: 256 blocks x 1024 threads, cooperative ----
// block b owns rows j in [8b, 8b+8). thread t: jj = t>>7, lane-group l = t&127,
// covers i = l + 128k, k=0..15 (coalesced, wave-uniform row).
__global__ void __launch_bounds__(1024, 4)
crf_main(const float* __restrict__ feats,
         const float* __restrict__ trans,
         const float* __restrict__ tstop,
         float* __restrict__ out) {
    cg::grid_group grid = cg::this_grid();
    const int b   = blockIdx.x;
    const int tid = threadIdx.x;
    const int jj  = tid >> 7;
    const int l   = tid & 127;
    const int j   = b * 8 + jj;
    const float* trow = trans + (size_t)j * NT;
    __shared__ float part[16];

    int par = 0;
    for (int t = 1; t < SEQ; ++t) {
        const float* g = g_fv[par];
        const float s = g[0];   // global shift; fv spread is bounded
        float acc = 0.f;
        #pragma unroll
        for (int k = 0; k < 16; ++k) {
            int i = l + (k << 7);
            acc += exp2f((g[i] - s) + trow[i] * LOG2E);
        }
        #pragma unroll
        for (int m = 1; m < 64; m <<= 1) acc += __shfl_xor(acc, m, 64);
        if ((tid & 63) == 0) part[tid >> 6] = acc;
        __syncthreads();
        if (tid < 8) {
            float S = part[2 * tid] + part[2 * tid + 1];
            g_fv[par ^ 1][b * 8 + tid] =
                s + __log2f(S) + feats[(size_t)t * NT + b * 8 + tid] * LOG2E;
        }
        par ^= 1;
        grid.sync();
    }

    // ---- final logsumexp with stop transitions + subtract gold ----
    if (b == 0) {
        const float* g = g_fv[par];
        const float s = g[0];
        float acc = 0.f;
        for (int j2 = tid; j2 < NT; j2 += 1024)
            acc += exp2f((g[j2] - s) + tstop[j2] * LOG2E);
        #pragma unroll
        for (int m = 1; m < 64; m <<= 1) acc += __shfl_xor(acc, m, 64);
        if ((tid & 63) == 0) part[tid >> 6] = acc;
        __syncthreads();
        if (tid == 0) {
            float S = 0.f;
            #pragma unroll
            for (int w = 0; w < 16; ++w) S += part[w];
            float fwd = (s + __log2f(S)) * LN2;
            out[0] = fwd - g_gold;
        }
    }
}

extern "C" void kernel_launch(void* const* d_in, const int* in_sizes, int n_in,
                              void* d_out, int out_size, void* d_ws, size_t ws_size,
                              hipStream_t stream) {
    const float* feats  = (const float*)d_in[0];
    const float* trans  = (const float*)d_in[1];
    const float* tstart = (const float*)d_in[2];
    const float* tstop  = (const float*)d_in[3];
    const int*   tags   = (const int*)d_in[4];
    float* out = (float*)d_out;

    hipLaunchKernelGGL(crf_init, dim3(2), dim3(1024), 0, stream, feats, tstart);
    hipLaunchKernelGGL(crf_gold, dim3(1), dim3(1024), 0, stream,
                       feats, trans, tstart, tstop, tags);

    void* args[] = { (void*)&feats, (void*)&trans, (void*)&tstop, (void*)&out };
    hipLaunchCooperativeKernel((void*)crf_main, dim3(256), dim3(1024),
                               args, 0, stream);
}